// Round 1
// 71.418 us; speedup vs baseline: 1.0174x; 1.0174x over previous
//
#include <hip/hip_runtime.h>

// Quanvolution: 802816 independent 4-qubit sims.
// R7 restructuring: the pre-gate state is a REAL trig-product vector
// t[k] = prod_w (bit_w(k) ? sin : cos)(pixel_w/2), so the whole circuit is one
// shared complex 16x16 matrix Mfull = P2*U2*P1*U1 applied to a real K=16
// vector. Mfull is built ONCE by a 1-block setup kernel into d_ws (params-only),
// zero-padded to K=32 so the verified mfma_f32_16x16x32_f16 path is unchanged.
// Main kernel: no W build, no Gs/Wt LDS, ZERO barriers (per-wave LDS only),
// 6 blocks/CU. Epilogue (|amp|^2 in-wave LDS transpose + sign sums) verbatim
// from the verified R4/R5 kernel.

typedef _Float16 f16;
typedef _Float16 half8 __attribute__((ext_vector_type(8)));
typedef float f4 __attribute__((ext_vector_type(4)));

#define PK2(a, b) __builtin_bit_cast(float, __builtin_amdgcn_cvt_pkrtz((a), (b)))

__device__ __forceinline__ float2 cmulf(float2 a, float2 b) {
    return make_float2(fmaf(a.x, b.x, -(a.y * b.y)),
                       fmaf(a.x, b.y,   a.y * b.x));
}

// ---- kernel 0 (1 block): Mfull = (P2 U2 P1) * U1kron, written as f16 ----
// Layout (2 KiB): wg[n*32 + k]; rows n=0..15 = Re Mfull[n][k], rows 16..31 =
// Im Mfull[n-16][k]; k=16..31 zero-padded (B-side zeros for the padded K=32).
__global__ void build_w_kernel(const float* __restrict__ params,
                               f16* __restrict__ wg) {
    __shared__ float4 Gs[8];   // SU(2) gates {ax,ay,bx,by}; [0..3]=L1, [4..7]=L2
    const int t = threadIdx.x;
    if (t < 8) {
        const float* pg = params + t * 3;
        const float ha = 0.5f * pg[0], hb = 0.5f * pg[1], hc = 0.5f * pg[2];
        const float sa = __sinf(ha), ca = __cosf(ha);
        const float sb = __sinf(hb), cb = __cosf(hb);
        const float sc = __sinf(hc), cx = __cosf(hc);
        Gs[t] = make_float4(cx*ca*cb + sc*sa*sb,      // ax
                            -(cx*ca*sb + sc*sa*cb),   // ay
                            sc*ca*sb - cx*sa*cb,      // bx
                            cx*sa*sb - sc*ca*cb);     // by
    }
    __syncthreads();

    // CNOT-ring perm (both layers): verified nibble tables from R4/R5.
    const unsigned long long IDX1P = 0x497a2f1c85b6e3d0ULL;
    const unsigned long long INV1P = 0xa3185ce7d46f2b90ULL;
    const int i = t >> 4;   // output amplitude (row of Mfull)
    const int m = t & 15;   // input amplitude  (col of Mfull)
    const int jN = (int)((IDX1P >> (i * 4)) & 15);
    float accx = 0.f, accy = 0.f;
    for (int k = 0; k < 16; ++k) {
        const int kN = (int)((INV1P >> (k * 4)) & 15);
        float2 a = make_float2(1.f, 0.f);   // (P2 U2 P1)[i][k]
        float2 b = make_float2(1.f, 0.f);   // U1kron[k][m]
#pragma unroll
        for (int w = 0; w < 4; ++w) {
            // u[0][0]=(ax,ay) u[0][1]=(bx,by) u[1][0]=(-bx,by) u[1][1]=(ax,-ay)
            const float4 g2 = Gs[4 + w];
            const int jb = (jN >> (3 - w)) & 1;
            const int kb = (kN >> (3 - w)) & 1;
            const float ux = jb ? (kb ?  g2.x : -g2.z) : (kb ? g2.z : g2.x);
            const float uy = jb ? (kb ? -g2.y :  g2.w) : (kb ? g2.w : g2.y);
            a = cmulf(a, make_float2(ux, uy));
            const float4 g1 = Gs[w];
            const int kb1 = (k >> (3 - w)) & 1;   // row bit of U1
            const int mb  = (m >> (3 - w)) & 1;   // col bit of U1
            const float vx = kb1 ? (mb ?  g1.x : -g1.z) : (mb ? g1.z : g1.x);
            const float vy = kb1 ? (mb ? -g1.y :  g1.w) : (mb ? g1.w : g1.y);
            b = cmulf(b, make_float2(vx, vy));
        }
        const float2 ab = cmulf(a, b);
        accx += ab.x;
        accy += ab.y;
    }
    wg[i * 32 + m]             = (f16)accx;
    wg[i * 32 + 16 + m]        = (f16)0.f;
    wg[(16 + i) * 32 + m]      = (f16)accy;
    wg[(16 + i) * 32 + 16 + m] = (f16)0.f;
}

// ---- main kernel: barrier-free, per-wave LDS only ----
__global__ __launch_bounds__(256, 6) void quanv_kernel(
        const float* __restrict__ x,    // (4096, 28, 28)
        const f16*   __restrict__ wg,   // 2 KiB shared matrix (L2-broadcast)
        float* __restrict__ out)        // (4096, 196*4)
{
    __shared__ __align__(16) unsigned char SB[4][5120]; // per-wave: states, prb

    const int t = threadIdx.x;
    const int gid = blockIdx.x * 256 + t;      // patch id: n*196 + r*14 + c

    // x loads first: HBM latency hides behind trig + W loads
    const int n = gid / 196;
    const int p = gid - n * 196;
    const int r = p / 14;
    const int c = p - r * 14;
    const float* xb = x + n * 784 + r * 56 + c * 2;   // 8B aligned
    const float2 top = *(const float2*)(xb);
    const float2 bot = *(const float2*)(xb + 28);

    const int l   = t & 63;          // lane
    const int wid = t >> 6;          // wave id
    const int q   = l >> 4;          // quad
    const int c16 = l & 15;

    // B fragments straight from global (same 2 KiB for all blocks -> L2 hit).
    // b0: cols 0..15 (Re out), b1: cols 16..31 (Im out); k=q*8..+7, zero k>=16.
    const half8 b0 = *(const half8*)(wg + c16 * 32 + q * 8);
    const half8 b1 = *(const half8*)(wg + (16 + c16) * 32 + q * 8);

    // ---- real initial state: t16[k] = prod_w (bit ? sin : cos)(pixel_w/2) ----
    const float h0 = 0.5f * top.x, h1 = 0.5f * top.y;
    const float h2 = 0.5f * bot.x, h3 = 0.5f * bot.y;
    const float c0 = __cosf(h0), s0 = __sinf(h0);
    const float c1 = __cosf(h1), s1 = __sinf(h1);
    const float c2 = __cosf(h2), s2 = __sinf(h2);
    const float c3 = __cosf(h3), s3 = __sinf(h3);
    const float A0 = c0 * c1, A1 = c0 * s1, A2 = s0 * c1, A3 = s0 * s1;
    const float B0 = c2 * c3, B1 = c2 * s3, B2 = s2 * c3, B3 = s2 * s3;

    // A-operand rows: 16 f16 of data + 16 f16 zeros (padded K=32), stride 80B.
    f16* st = (f16*)(SB[wid] + l * 80);
    *(float4*)(st)      = make_float4(PK2(A0 * B0, A0 * B1), PK2(A0 * B2, A0 * B3),
                                      PK2(A1 * B0, A1 * B1), PK2(A1 * B2, A1 * B3));
    *(float4*)(st + 8)  = make_float4(PK2(A2 * B0, A2 * B1), PK2(A2 * B2, A2 * B3),
                                      PK2(A3 * B0, A3 * B1), PK2(A3 * B2, A3 * B3));
    const float4 zz = make_float4(0.f, 0.f, 0.f, 0.f);
    *(float4*)(st + 16) = zz;   // k=16..23 zero (avoid NaN*0 from junk LDS)
    *(float4*)(st + 24) = zz;   // k=24..31 zero

    // ---- MFMA: D[patch][n] = sum_k t16[patch][k] * B[k][n]  (in-wave DS order,
    // no barrier: write above / read below are same-wave, R4/R5-verified) ----
    const f4 zf4 = {0.f, 0.f, 0.f, 0.f};
    f4 d0[4], d1[4];
#pragma unroll
    for (int mm = 0; mm < 4; ++mm) {
        const half8 am = *(const half8*)(SB[wid] + (mm * 16 + c16) * 80 + q * 16);
        d0[mm] = __builtin_amdgcn_mfma_f32_16x16x32_f16(am, b0, zf4, 0, 0, 0);
        d1[mm] = __builtin_amdgcn_mfma_f32_16x16x32_f16(am, b1, zf4, 0, 0, 0);
    }

    // ---- |amp|^2 transpose via LDS (in-wave; verified R4/R5) ----
    // C/D layout: col=lane&15 (amp), row=quad*4+reg -> patch_local = mm*16+q*4+reg
    float* prb = (float*)SB[wid];   // reuse: [64 patches][20 floats]
#pragma unroll
    for (int mm = 0; mm < 4; ++mm)
#pragma unroll
        for (int reg = 0; reg < 4; ++reg) {
            const float pv = fmaf(d0[mm][reg], d0[mm][reg], d1[mm][reg] * d1[mm][reg]);
            prb[(mm * 16 + q * 4 + reg) * 20 + c16] = pv;   // 2-way banks: free
        }

    const float4 p0 = *(const float4*)(prb + l * 20);
    const float4 p1 = *(const float4*)(prb + l * 20 + 4);
    const float4 p2 = *(const float4*)(prb + l * 20 + 8);
    const float4 p3 = *(const float4*)(prb + l * 20 + 12);

    // <Z_w>: amp i = a*8+b*4+c*2+d, wire0=a ... wire3=d
    const float t00 = p0.x + p0.y + p0.z + p0.w;
    const float t01 = p1.x + p1.y + p1.z + p1.w;
    const float t10 = p2.x + p2.y + p2.z + p2.w;
    const float t11 = p3.x + p3.y + p3.z + p3.w;
    const float e0 = (t00 + t01) - (t10 + t11);
    const float e1 = (t00 - t01) + (t10 - t11);

    const float u00 = p0.x + p1.x + p2.x + p3.x;
    const float u01 = p0.y + p1.y + p2.y + p3.y;
    const float u10 = p0.z + p1.z + p2.z + p3.z;
    const float u11 = p0.w + p1.w + p2.w + p3.w;
    const float e2 = (u00 + u01) - (u10 + u11);
    const float e3 = (u00 - u01) + (u10 - u11);

    *(float4*)(out + gid * 4) = make_float4(e0, e1, e2, e3);
}

extern "C" void kernel_launch(void* const* d_in, const int* in_sizes, int n_in,
                              void* d_out, int out_size, void* d_ws, size_t ws_size,
                              hipStream_t stream) {
    const float* x      = (const float*)d_in[0];   // 4096*28*28
    const float* params = (const float*)d_in[1];   // 2*4*3
    float* out = (float*)d_out;                    // 4096*784
    f16* wg = (f16*)d_ws;                          // 2 KiB of workspace

    build_w_kernel<<<1, 256, 0, stream>>>(params, wg);
    const int npatch = 4096 * 196;                 // 802816, divisible by 256
    quanv_kernel<<<npatch / 256, 256, 0, stream>>>(x, wg, out);
}

// Round 3
// 71.035 us; speedup vs baseline: 1.0229x; 1.0054x over previous
//
#include <hip/hip_runtime.h>

// Quanvolution: 802816 independent 4-qubit sims.
// R8 (resubmit after infra failure): two patches per thread. Patch pairs
// (2j,2j+1) share image/row and a 16B-aligned 4-pixel span per pixel row ->
// float4 x loads, one index chain, shared wg B-fragments, half the waves
// (6272). Per-wave MFMA/LDS core is the verified R7 structure run twice
// (phase A/B) in the same per-wave 5KB region (in-wave DS ordering,
// barrier-free). Circuit = one shared complex 16x16 Mfull = P2*U2*P1*U1
// (params-only, built once by a 1-block setup kernel into d_ws), applied to
// the REAL trig-product vector t[k] via mfma_f32_16x16x32_f16, K padded 16->32.

typedef _Float16 f16;
typedef _Float16 half8 __attribute__((ext_vector_type(8)));
typedef float f4 __attribute__((ext_vector_type(4)));

#define PK2(a, b) __builtin_bit_cast(float, __builtin_amdgcn_cvt_pkrtz((a), (b)))

__device__ __forceinline__ float2 cmulf(float2 a, float2 b) {
    return make_float2(fmaf(a.x, b.x, -(a.y * b.y)),
                       fmaf(a.x, b.y,   a.y * b.x));
}

// ---- kernel 0 (1 block): Mfull = (P2 U2 P1) * U1kron, written as f16 ----
// Layout (2 KiB): wg[n*32 + k]; rows n=0..15 = Re Mfull[n][k], rows 16..31 =
// Im Mfull[n-16][k]; k=16..31 zero-padded (B-side zeros for the padded K=32).
__global__ void build_w_kernel(const float* __restrict__ params,
                               f16* __restrict__ wg) {
    __shared__ float4 Gs[8];   // SU(2) gates {ax,ay,bx,by}; [0..3]=L1, [4..7]=L2
    const int t = threadIdx.x;
    if (t < 8) {
        const float* pg = params + t * 3;
        const float ha = 0.5f * pg[0], hb = 0.5f * pg[1], hc = 0.5f * pg[2];
        const float sa = __sinf(ha), ca = __cosf(ha);
        const float sb = __sinf(hb), cb = __cosf(hb);
        const float sc = __sinf(hc), cx = __cosf(hc);
        Gs[t] = make_float4(cx*ca*cb + sc*sa*sb,      // ax
                            -(cx*ca*sb + sc*sa*cb),   // ay
                            sc*ca*sb - cx*sa*cb,      // bx
                            cx*sa*sb - sc*ca*cb);     // by
    }
    __syncthreads();

    // CNOT-ring perm (both layers): verified nibble tables from R4/R5.
    const unsigned long long IDX1P = 0x497a2f1c85b6e3d0ULL;
    const unsigned long long INV1P = 0xa3185ce7d46f2b90ULL;
    const int i = t >> 4;   // output amplitude (row of Mfull)
    const int m = t & 15;   // input amplitude  (col of Mfull)
    const int jN = (int)((IDX1P >> (i * 4)) & 15);
    float accx = 0.f, accy = 0.f;
    for (int k = 0; k < 16; ++k) {
        const int kN = (int)((INV1P >> (k * 4)) & 15);
        float2 a = make_float2(1.f, 0.f);   // (P2 U2 P1)[i][k]
        float2 b = make_float2(1.f, 0.f);   // U1kron[k][m]
#pragma unroll
        for (int w = 0; w < 4; ++w) {
            // u[0][0]=(ax,ay) u[0][1]=(bx,by) u[1][0]=(-bx,by) u[1][1]=(ax,-ay)
            const float4 g2 = Gs[4 + w];
            const int jb = (jN >> (3 - w)) & 1;
            const int kb = (kN >> (3 - w)) & 1;
            const float ux = jb ? (kb ?  g2.x : -g2.z) : (kb ? g2.z : g2.x);
            const float uy = jb ? (kb ? -g2.y :  g2.w) : (kb ? g2.w : g2.y);
            a = cmulf(a, make_float2(ux, uy));
            const float4 g1 = Gs[w];
            const int kb1 = (k >> (3 - w)) & 1;   // row bit of U1
            const int mb  = (m >> (3 - w)) & 1;   // col bit of U1
            const float vx = kb1 ? (mb ?  g1.x : -g1.z) : (mb ? g1.z : g1.x);
            const float vy = kb1 ? (mb ? -g1.y :  g1.w) : (mb ? g1.w : g1.y);
            b = cmulf(b, make_float2(vx, vy));
        }
        const float2 ab = cmulf(a, b);
        accx += ab.x;
        accy += ab.y;
    }
    wg[i * 32 + m]             = (f16)accx;
    wg[i * 32 + 16 + m]        = (f16)0.f;
    wg[(16 + i) * 32 + m]      = (f16)accy;
    wg[(16 + i) * 32 + 16 + m] = (f16)0.f;
}

// ---- main kernel: barrier-free, per-wave LDS only, 2 patches/thread ----
__global__ __launch_bounds__(256, 6) void quanv_kernel(
        const float* __restrict__ x,    // (4096, 28, 28)
        const f16*   __restrict__ wg,   // 2 KiB shared matrix (L2-broadcast)
        float* __restrict__ out)        // (4096, 196*4)
{
    __shared__ __align__(16) unsigned char SB[4][5120]; // per-wave: states, prb

    const int t = threadIdx.x;
    const int g = blockIdx.x * 256 + t;        // pair id: patches 2g, 2g+1
    // 98 pairs/image, 7 pairs/patch-row; pairs never straddle image or row.
    const int n  = g / 98;
    const int pp = g - n * 98;
    const int r  = pp / 7;
    const int cc = pp - r * 7;                 // pair column 0..6 (patch col 2cc)

    // x loads first: HBM latency hides behind trig. 16B aligned float4s.
    const float* xb = x + n * 784 + r * 56 + cc * 4;
    const float4 top = *(const float4*)(xb);
    const float4 bot = *(const float4*)(xb + 28);

    const int l   = t & 63;          // lane
    const int wid = t >> 6;          // wave id
    const int q   = l >> 4;          // quad
    const int c16 = l & 15;

    // B fragments straight from global (same 2 KiB for all blocks -> L2 hit).
    const half8 b0 = *(const half8*)(wg + c16 * 32 + q * 8);        // Re out
    const half8 b1 = *(const half8*)(wg + (16 + c16) * 32 + q * 8); // Im out

    // trig for all 8 pixels up front (ILP)
    const float px[2][4] = {{top.x, top.y, bot.x, bot.y},
                            {top.z, top.w, bot.z, bot.w}};
    float cs[2][4], sn[2][4];
#pragma unroll
    for (int ph = 0; ph < 2; ++ph)
#pragma unroll
        for (int w = 0; w < 4; ++w) {
            const float h = 0.5f * px[ph][w];
            cs[ph][w] = __cosf(h);
            sn[ph][w] = __sinf(h);
        }

    const f4 zf4 = {0.f, 0.f, 0.f, 0.f};
    const float4 zz = make_float4(0.f, 0.f, 0.f, 0.f);
    float4 res[2];

#pragma unroll
    for (int ph = 0; ph < 2; ++ph) {
        // real initial state t16[k] = prod_w (bit ? sin : cos)(pixel_w/2)
        const float A0 = cs[ph][0] * cs[ph][1], A1 = cs[ph][0] * sn[ph][1];
        const float A2 = sn[ph][0] * cs[ph][1], A3 = sn[ph][0] * sn[ph][1];
        const float B0 = cs[ph][2] * cs[ph][3], B1 = cs[ph][2] * sn[ph][3];
        const float B2 = sn[ph][2] * cs[ph][3], B3 = sn[ph][2] * sn[ph][3];

        // A-operand row: 16 f16 data + 16 f16 zeros (padded K=32), stride 80B.
        f16* st = (f16*)(SB[wid] + l * 80);
        *(float4*)(st)      = make_float4(PK2(A0*B0, A0*B1), PK2(A0*B2, A0*B3),
                                          PK2(A1*B0, A1*B1), PK2(A1*B2, A1*B3));
        *(float4*)(st + 8)  = make_float4(PK2(A2*B0, A2*B1), PK2(A2*B2, A2*B3),
                                          PK2(A3*B0, A3*B1), PK2(A3*B2, A3*B3));
        *(float4*)(st + 16) = zz;   // zero pad k=16..31 (prb clobbers each phase)
        *(float4*)(st + 24) = zz;

        // MFMA: D[patch][amp] = sum_k t16[patch][k] * B[k][amp]
        // (in-wave DS order, barrier-free; verified R4/R5/R7)
        f4 d0[4], d1[4];
#pragma unroll
        for (int mm = 0; mm < 4; ++mm) {
            const half8 am = *(const half8*)(SB[wid] + (mm*16 + c16)*80 + q*16);
            d0[mm] = __builtin_amdgcn_mfma_f32_16x16x32_f16(am, b0, zf4, 0, 0, 0);
            d1[mm] = __builtin_amdgcn_mfma_f32_16x16x32_f16(am, b1, zf4, 0, 0, 0);
        }

        // |amp|^2 transpose via LDS (in-wave; verified). C/D layout:
        // col=lane&15 (amp), row=quad*4+reg -> patch_local = mm*16+q*4+reg
        float* prb = (float*)SB[wid];   // reuse: [64 patches][20 floats]
#pragma unroll
        for (int mm = 0; mm < 4; ++mm)
#pragma unroll
            for (int reg = 0; reg < 4; ++reg) {
                const float pv = fmaf(d0[mm][reg], d0[mm][reg],
                                      d1[mm][reg] * d1[mm][reg]);
                prb[(mm*16 + q*4 + reg) * 20 + c16] = pv;   // 2-way banks: free
            }

        const float4 p0 = *(const float4*)(prb + l * 20);
        const float4 p1 = *(const float4*)(prb + l * 20 + 4);
        const float4 p2 = *(const float4*)(prb + l * 20 + 8);
        const float4 p3 = *(const float4*)(prb + l * 20 + 12);

        // <Z_w>: amp i = a*8+b*4+c*2+d, wire0=a ... wire3=d
        const float t00 = p0.x + p0.y + p0.z + p0.w;
        const float t01 = p1.x + p1.y + p1.z + p1.w;
        const float t10 = p2.x + p2.y + p2.z + p2.w;
        const float t11 = p3.x + p3.y + p3.z + p3.w;
        const float e0 = (t00 + t01) - (t10 + t11);
        const float e1 = (t00 - t01) + (t10 - t11);

        const float u00 = p0.x + p1.x + p2.x + p3.x;
        const float u01 = p0.y + p1.y + p2.y + p3.y;
        const float u10 = p0.z + p1.z + p2.z + p3.z;
        const float u11 = p0.w + p1.w + p2.w + p3.w;
        const float e2 = (u00 + u01) - (u10 + u11);
        const float e3 = (u00 - u01) + (u10 - u11);
        res[ph] = make_float4(e0, e1, e2, e3);
    }

    // patches 2g and 2g+1: 32B contiguous per lane
    *(float4*)(out + g * 8)     = res[0];
    *(float4*)(out + g * 8 + 4) = res[1];
}

extern "C" void kernel_launch(void* const* d_in, const int* in_sizes, int n_in,
                              void* d_out, int out_size, void* d_ws, size_t ws_size,
                              hipStream_t stream) {
    const float* x      = (const float*)d_in[0];   // 4096*28*28
    const float* params = (const float*)d_in[1];   // 2*4*3
    float* out = (float*)d_out;                    // 4096*784
    f16* wg = (f16*)d_ws;                          // 2 KiB of workspace

    build_w_kernel<<<1, 256, 0, stream>>>(params, wg);
    const int npairs = 4096 * 98;                  // 401408, divisible by 256
    quanv_kernel<<<npairs / 256, 256, 0, stream>>>(x, wg, out);
}

// Round 4
// 70.038 us; speedup vs baseline: 1.0375x; 1.0142x over previous
//
#include <hip/hip_runtime.h>

// Quanvolution: 802816 independent 4-qubit sims.
// R9: single fused kernel. The Mfull = (P2 U2 P1) * U1kron build is done
// in-block, BIT-IDENTICALLY to R8's separate build_w kernel: 256 threads stage
// A-entries (P2U2P1) and B-entries (U1kron) as f32 complex in LDS, then each
// thread computes one Mfull entry with the same cmulf/sum-order/(f16)-cast
// sequence. Removes the build_w dispatch + inter-kernel gap from the timed
// graph. Main path is verbatim R8: 2 patches/thread (float4 x loads), real
// trig-product state t[k], K zero-padded 16->32, mfma_f32_16x16x32_f16,
// barrier-free per-wave LDS (states + |amp|^2 transpose), 6 blocks/CU.

typedef _Float16 f16;
typedef _Float16 half8 __attribute__((ext_vector_type(8)));
typedef float f4 __attribute__((ext_vector_type(4)));

#define PK2(a, b) __builtin_bit_cast(float, __builtin_amdgcn_cvt_pkrtz((a), (b)))

__device__ __forceinline__ float2 cmulf(float2 a, float2 b) {
    return make_float2(fmaf(a.x, b.x, -(a.y * b.y)),
                       fmaf(a.x, b.y,   a.y * b.x));
}

__global__ __launch_bounds__(256, 6) void quanv_kernel(
        const float* __restrict__ x,       // (4096, 28, 28)
        const float* __restrict__ params,  // (2, 4, 3)
        float* __restrict__ out)           // (4096, 196*4)
{
    __shared__ float4 Gs[8];                            // gates {ax,ay,bx,by}
    __shared__ __align__(16) unsigned char SB[4][5120]; // per-wave: states, prb
    __shared__ __align__(16) f16 WG[32 * 40];           // Mfull, 80B rows

    const int t = threadIdx.x;
    const int g = blockIdx.x * 256 + t;        // pair id: patches 2g, 2g+1
    // 98 pairs/image, 7 pairs/patch-row; pairs never straddle image or row.
    const int n  = g / 98;
    const int pp = g - n * 98;
    const int r  = pp / 7;
    const int cc = pp - r * 7;                 // pair column 0..6

    // x loads first: HBM latency hides behind the whole Mfull build phase.
    const float* xb = x + n * 784 + r * 56 + cc * 4;   // 16B aligned
    const float4 top = *(const float4*)(xb);
    const float4 bot = *(const float4*)(xb + 28);

    // ---- gates: U = RX(p2/2) RZ(p1/2) RY(p0/2) = [[a,b],[-conj(b),conj(a)]] ----
    if (t < 8) {
        const float* pg = params + t * 3;
        const float ha = 0.5f * pg[0], hb = 0.5f * pg[1], hc = 0.5f * pg[2];
        const float sa = __sinf(ha), ca = __cosf(ha);
        const float sb = __sinf(hb), cb = __cosf(hb);
        const float sc = __sinf(hc), cx = __cosf(hc);
        Gs[t] = make_float4(cx*ca*cb + sc*sa*sb,      // ax
                            -(cx*ca*sb + sc*sa*cb),   // ay
                            sc*ca*sb - cx*sa*cb,      // bx
                            cx*sa*sb - sc*ca*cb);     // by
    }
    __syncthreads();

    // ---- stage A = P2*U2*P1 and B = U1kron entries (f32 complex, in SB[0]) ----
    // A[i][k]: product of 4 U2-gate entries through the CNOT-ring perms.
    // B[k][m]: product of 4 U1-gate entries. One entry of each per thread.
    float2* Af = (float2*)(SB[0]);             // [16][16] complex, 2048 B
    float2* Bf = (float2*)(SB[0] + 2048);      // [16][16] complex, 2048 B
    {
        const unsigned long long IDX1P = 0x497a2f1c85b6e3d0ULL;
        const unsigned long long INV1P = 0xa3185ce7d46f2b90ULL;
        const int hi = t >> 4, lo = t & 15;
        const int jN = (int)((IDX1P >> (hi * 4)) & 15);
        const int kN = (int)((INV1P >> (lo * 4)) & 15);
        float2 a = make_float2(1.f, 0.f);   // A[hi][lo]
        float2 b = make_float2(1.f, 0.f);   // B[hi][lo]
#pragma unroll
        for (int w = 0; w < 4; ++w) {
            // u[0][0]=(ax,ay) u[0][1]=(bx,by) u[1][0]=(-bx,by) u[1][1]=(ax,-ay)
            const float4 g2 = Gs[4 + w];
            const int jb = (jN >> (3 - w)) & 1;
            const int kb = (kN >> (3 - w)) & 1;
            const float ux = jb ? (kb ?  g2.x : -g2.z) : (kb ? g2.z : g2.x);
            const float uy = jb ? (kb ? -g2.y :  g2.w) : (kb ? g2.w : g2.y);
            a = cmulf(a, make_float2(ux, uy));
            const float4 g1 = Gs[w];
            const int kb1 = (hi >> (3 - w)) & 1;   // row bit of U1
            const int mb  = (lo >> (3 - w)) & 1;   // col bit of U1
            const float vx = kb1 ? (mb ?  g1.x : -g1.z) : (mb ? g1.z : g1.x);
            const float vy = kb1 ? (mb ? -g1.y :  g1.w) : (mb ? g1.w : g1.y);
            b = cmulf(b, make_float2(vx, vy));
        }
        Af[hi * 16 + lo] = a;
        Bf[hi * 16 + lo] = b;
    }
    __syncthreads();

    // ---- Mfull[i][m] = sum_k A[i][k]*B[k][m]: same f32 ops/order as build_w ----
    {
        const int i = t >> 4, m = t & 15;
        float accx = 0.f, accy = 0.f;
#pragma unroll
        for (int k = 0; k < 16; ++k) {
            const float2 ab = cmulf(Af[i * 16 + k], Bf[k * 16 + m]);
            accx += ab.x;
            accy += ab.y;
        }
        // rows i: Re, rows 16+i: Im; cols 16..31 zero (padded K=32)
        WG[i * 40 + m]              = (f16)accx;
        WG[i * 40 + 16 + m]         = (f16)0.f;
        WG[(16 + i) * 40 + m]       = (f16)accy;
        WG[(16 + i) * 40 + 16 + m]  = (f16)0.f;
    }
    __syncthreads();   // WG ready; SB free for per-wave use. Barrier-free below.

    const int l   = t & 63;          // lane
    const int wid = t >> 6;          // wave id
    const int q   = l >> 4;          // quad
    const int c16 = l & 15;

    // B fragments from LDS (stride-40 rows: 2-way banks, 16B aligned)
    const half8 b0 = *(const half8*)&WG[c16 * 40 + q * 8];        // Re out
    const half8 b1 = *(const half8*)&WG[(16 + c16) * 40 + q * 8]; // Im out

    // trig for all 8 pixels up front (ILP)
    const float px[2][4] = {{top.x, top.y, bot.x, bot.y},
                            {top.z, top.w, bot.z, bot.w}};
    float cs[2][4], sn[2][4];
#pragma unroll
    for (int ph = 0; ph < 2; ++ph)
#pragma unroll
        for (int w = 0; w < 4; ++w) {
            const float h = 0.5f * px[ph][w];
            cs[ph][w] = __cosf(h);
            sn[ph][w] = __sinf(h);
        }

    const f4 zf4 = {0.f, 0.f, 0.f, 0.f};
    const float4 zz = make_float4(0.f, 0.f, 0.f, 0.f);
    float4 res[2];

#pragma unroll
    for (int ph = 0; ph < 2; ++ph) {
        // real initial state t16[k] = prod_w (bit ? sin : cos)(pixel_w/2)
        const float A0 = cs[ph][0] * cs[ph][1], A1 = cs[ph][0] * sn[ph][1];
        const float A2 = sn[ph][0] * cs[ph][1], A3 = sn[ph][0] * sn[ph][1];
        const float B0 = cs[ph][2] * cs[ph][3], B1 = cs[ph][2] * sn[ph][3];
        const float B2 = sn[ph][2] * cs[ph][3], B3 = sn[ph][2] * sn[ph][3];

        // A-operand row: 16 f16 data + 16 f16 zeros (padded K=32), stride 80B.
        f16* st = (f16*)(SB[wid] + l * 80);
        *(float4*)(st)      = make_float4(PK2(A0*B0, A0*B1), PK2(A0*B2, A0*B3),
                                          PK2(A1*B0, A1*B1), PK2(A1*B2, A1*B3));
        *(float4*)(st + 8)  = make_float4(PK2(A2*B0, A2*B1), PK2(A2*B2, A2*B3),
                                          PK2(A3*B0, A3*B1), PK2(A3*B2, A3*B3));
        *(float4*)(st + 16) = zz;   // zero pad k=16..31 (prb clobbers each phase)
        *(float4*)(st + 24) = zz;

        // MFMA: D[patch][amp] = sum_k t16[patch][k] * B[k][amp]
        // (in-wave DS order, barrier-free; verified R4/R5/R7/R8)
        f4 d0[4], d1[4];
#pragma unroll
        for (int mm = 0; mm < 4; ++mm) {
            const half8 am = *(const half8*)(SB[wid] + (mm*16 + c16)*80 + q*16);
            d0[mm] = __builtin_amdgcn_mfma_f32_16x16x32_f16(am, b0, zf4, 0, 0, 0);
            d1[mm] = __builtin_amdgcn_mfma_f32_16x16x32_f16(am, b1, zf4, 0, 0, 0);
        }

        // |amp|^2 transpose via LDS (in-wave; verified). C/D layout:
        // col=lane&15 (amp), row=quad*4+reg -> patch_local = mm*16+q*4+reg
        float* prb = (float*)SB[wid];   // reuse: [64 patches][20 floats]
#pragma unroll
        for (int mm = 0; mm < 4; ++mm)
#pragma unroll
            for (int reg = 0; reg < 4; ++reg) {
                const float pv = fmaf(d0[mm][reg], d0[mm][reg],
                                      d1[mm][reg] * d1[mm][reg]);
                prb[(mm*16 + q*4 + reg) * 20 + c16] = pv;   // 2-way banks: free
            }

        const float4 p0 = *(const float4*)(prb + l * 20);
        const float4 p1 = *(const float4*)(prb + l * 20 + 4);
        const float4 p2 = *(const float4*)(prb + l * 20 + 8);
        const float4 p3 = *(const float4*)(prb + l * 20 + 12);

        // <Z_w>: amp i = a*8+b*4+c*2+d, wire0=a ... wire3=d
        const float t00 = p0.x + p0.y + p0.z + p0.w;
        const float t01 = p1.x + p1.y + p1.z + p1.w;
        const float t10 = p2.x + p2.y + p2.z + p2.w;
        const float t11 = p3.x + p3.y + p3.z + p3.w;
        const float e0 = (t00 + t01) - (t10 + t11);
        const float e1 = (t00 - t01) + (t10 - t11);

        const float u00 = p0.x + p1.x + p2.x + p3.x;
        const float u01 = p0.y + p1.y + p2.y + p3.y;
        const float u10 = p0.z + p1.z + p2.z + p3.z;
        const float u11 = p0.w + p1.w + p2.w + p3.w;
        const float e2 = (u00 + u01) - (u10 + u11);
        const float e3 = (u00 - u01) + (u10 - u11);
        res[ph] = make_float4(e0, e1, e2, e3);
    }

    // patches 2g and 2g+1: 32B contiguous per lane
    *(float4*)(out + g * 8)     = res[0];
    *(float4*)(out + g * 8 + 4) = res[1];
}

extern "C" void kernel_launch(void* const* d_in, const int* in_sizes, int n_in,
                              void* d_out, int out_size, void* d_ws, size_t ws_size,
                              hipStream_t stream) {
    const float* x      = (const float*)d_in[0];   // 4096*28*28
    const float* params = (const float*)d_in[1];   // 2*4*3
    float* out = (float*)d_out;                    // 4096*784

    const int npairs = 4096 * 98;                  // 401408, divisible by 256
    quanv_kernel<<<npairs / 256, 256, 0, stream>>>(x, params, out);
}